// Round 1
// baseline (236.441 us; speedup 1.0000x reference)
//
#include <hip/hip_runtime.h>
#include <math.h>

#define NPTS 16384
#define NB   2
#define QB   256           // queries per block (= threads)
#define RCH  2048          // refs per chunk
#define NQC  (NPTS / QB)   // 64
#define NRC  (NPTS / RCH)  // 8
#define TOTMIN (2 * NB * NPTS)  // 65536 per-query mins (fwd + bwd)

__global__ __launch_bounds__(256) void init_min_kernel(unsigned int* w) {
    int i = blockIdx.x * 256 + threadIdx.x;
    w[i] = 0x7F800000u;  // +inf bits
}

// Each thread owns one query point; loops over a chunk of reference points.
// Reference loads are wave-uniform (same address for all lanes) -> expect
// the compiler to scalarize them into s_load with __restrict__.
__global__ __launch_bounds__(QB) void nn_min_kernel(const float* __restrict__ q,
                                                    const float* __restrict__ r,
                                                    unsigned int* __restrict__ omin) {
    const int qi = blockIdx.y * QB + threadIdx.x;   // query index within batch
    const int b  = blockIdx.z;                      // batch
    const int rbase = b * NPTS + blockIdx.x * RCH;  // ref chunk start (global idx)

    const float* qp = q + (size_t)(b * NPTS + qi) * 3;
    const float qx = qp[0], qy = qp[1], qz = qp[2];

    const float4* rp = (const float4*)(r + (size_t)rbase * 3);  // 16B-aligned (rbase*12 % 16 == 0)

    // 4 independent min accumulators to break the v_min dependency chain.
    float m0 = INFINITY, m1 = INFINITY, m2 = INFINITY, m3 = INFINITY;

    #pragma unroll 4
    for (int j = 0; j < RCH / 4; ++j) {
        float4 f0 = rp[3 * j + 0];
        float4 f1 = rp[3 * j + 1];
        float4 f2 = rp[3 * j + 2];
        float dx, dy, dz, d2;
        dx = qx - f0.x; dy = qy - f0.y; dz = qz - f0.z;
        d2 = dx * dx + dy * dy + dz * dz; m0 = fminf(m0, d2);
        dx = qx - f0.w; dy = qy - f1.x; dz = qz - f1.y;
        d2 = dx * dx + dy * dy + dz * dz; m1 = fminf(m1, d2);
        dx = qx - f1.z; dy = qy - f1.w; dz = qz - f2.x;
        d2 = dx * dx + dy * dy + dz * dz; m2 = fminf(m2, d2);
        dx = qx - f2.y; dy = qy - f2.z; dz = qz - f2.w;
        d2 = dx * dx + dy * dy + dz * dz; m3 = fminf(m3, d2);
    }

    float m = fminf(fminf(m0, m1), fminf(m2, m3));
    // squared distances are non-negative -> uint bit-compare == float compare
    atomicMin(&omin[b * NPTS + qi], __float_as_uint(m));
}

// mean(fwd_min) + mean(bwd_min) = sum(sqrt(all 65536 mins)) / 32768 since B*N == B*M
__global__ __launch_bounds__(256) void reduce_out_kernel(const unsigned int* __restrict__ mins,
                                                         float* __restrict__ out) {
    float s = 0.f;
    for (int i = threadIdx.x; i < TOTMIN; i += 256)
        s += sqrtf(__uint_as_float(mins[i]));
    #pragma unroll
    for (int off = 32; off > 0; off >>= 1)
        s += __shfl_down(s, off);
    __shared__ float wsum[4];
    const int lane = threadIdx.x & 63, w = threadIdx.x >> 6;
    if (lane == 0) wsum[w] = s;
    __syncthreads();
    if (threadIdx.x == 0)
        out[0] = (wsum[0] + wsum[1] + wsum[2] + wsum[3]) / (float)(NB * NPTS);
}

extern "C" void kernel_launch(void* const* d_in, const int* in_sizes, int n_in,
                              void* d_out, int out_size, void* d_ws, size_t ws_size,
                              hipStream_t stream) {
    const float* pred   = (const float*)d_in[0];
    const float* target = (const float*)d_in[1];
    unsigned int* mins  = (unsigned int*)d_ws;   // 65536 * 4B = 256 KiB scratch
    float* out          = (float*)d_out;

    init_min_kernel<<<TOTMIN / 256, 256, 0, stream>>>(mins);

    dim3 grid(NRC, NQC, NB);
    // forward: pred queries vs target refs
    nn_min_kernel<<<grid, QB, 0, stream>>>(pred, target, mins);
    // backward: target queries vs pred refs
    nn_min_kernel<<<grid, QB, 0, stream>>>(target, pred, mins + NB * NPTS);

    reduce_out_kernel<<<1, 256, 0, stream>>>(mins, out);
}

// Round 2
// 132.244 us; speedup vs baseline: 1.7879x; 1.7879x over previous
//
#include <hip/hip_runtime.h>
#include <math.h>

#define NPTS 16384
#define NB   2
#define QB   256
#define RCH  2048
#define NQC  (NPTS / QB)    // 64
#define NRC  (NPTS / RCH)   // 8
#define TOTQ (NB * NPTS)    // 32768 queries per direction
#define TOTMIN (2 * TOTQ)   // 65536

// monotone float -> uint mapping (preserves order for all finite floats)
__device__ __forceinline__ unsigned ordf(float f) {
    unsigned b = __float_as_uint(f);
    return (b & 0x80000000u) ? ~b : (b | 0x80000000u);
}
__device__ __forceinline__ float deordf(unsigned u) {
    return __uint_as_float((u & 0x80000000u) ? (u ^ 0x80000000u) : ~u);
}

// Pack (x,y,z,0.5*|p|^2) for both clouds; init the min array.
__global__ __launch_bounds__(256) void prep_kernel(const float* __restrict__ pred,
                                                   const float* __restrict__ target,
                                                   float4* __restrict__ ppk,
                                                   float4* __restrict__ tpk,
                                                   unsigned* __restrict__ mins) {
    int t = blockIdx.x * 256 + threadIdx.x;      // 0..TOTMIN-1
    const float* src = (t < TOTQ) ? pred : target;
    float4* dst      = (t < TOTQ) ? ppk : tpk;
    int i            = (t < TOTQ) ? t : t - TOTQ;
    float x = src[3 * i], y = src[3 * i + 1], z = src[3 * i + 2];
    dst[i] = make_float4(x, y, z, 0.5f * (x * x + y * y + z * z));
    mins[t] = 0xFFFFFFFFu;                       // ordf(+inf) upper bound
}

// Fused both-directions NN: min over refs of (0.5|r|^2 - q.r).
// Ref loads are wave-uniform float4 -> s_load_dwordx4; 4.5 VALU/pair.
__global__ __launch_bounds__(QB) void nn_min_kernel(const float4* __restrict__ ppk,
                                                    const float4* __restrict__ tpk,
                                                    unsigned* __restrict__ mins) {
    const int z = blockIdx.z;                    // 0..2*NB-1
    const int b = (z < NB) ? z : z - NB;
    const float4* qarr = (z < NB) ? ppk : tpk;
    const float4* rarr = (z < NB) ? tpk : ppk;

    const int qi = blockIdx.y * QB + threadIdx.x;
    float4 q = qarr[b * NPTS + qi];
    const float qx = q.x, qy = q.y, qz = q.z;

    const float4* rp = rarr + b * NPTS + blockIdx.x * RCH;

    float mA = INFINITY, mB = INFINITY;
    #pragma unroll 4
    for (int j = 0; j < RCH; j += 4) {
        float4 r0 = rp[j], r1 = rp[j + 1], r2 = rp[j + 2], r3 = rp[j + 3];
        float c0 = qx * r0.x + qy * r0.y + qz * r0.z;
        float c1 = qx * r1.x + qy * r1.y + qz * r1.z;
        float c2 = qx * r2.x + qy * r2.y + qz * r2.z;
        float c3 = qx * r3.x + qy * r3.y + qz * r3.z;
        float t0 = r0.w - c0, t1 = r1.w - c1;
        float t2 = r2.w - c2, t3 = r3.w - c3;
        mA = fminf(mA, fminf(t0, t1));           // -> v_min3
        mB = fminf(mB, fminf(t2, t3));           // -> v_min3
    }
    float m = fminf(mA, mB);
    atomicMin(&mins[z * NPTS + qi], ordf(m));
}

// Stage A: 64 blocks x 1024 mins each -> partial sums of sqrt(d^2).
__global__ __launch_bounds__(256) void reduceA_kernel(const unsigned* __restrict__ mins,
                                                      const float4* __restrict__ ppk,
                                                      const float4* __restrict__ tpk,
                                                      float* __restrict__ partials) {
    int base = blockIdx.x * 1024;
    float s = 0.f;
    #pragma unroll
    for (int k = 0; k < 4; ++k) {
        int t = base + k * 256 + threadIdx.x;
        float m = deordf(mins[t]);
        float w = (t < TOTQ) ? ppk[t].w : tpk[t - TOTQ].w;   // 0.5*|q|^2
        s += sqrtf(fmaxf(0.f, 2.f * (w + m)));               // d = sqrt(q2 + r2 - 2q.r)
    }
    #pragma unroll
    for (int off = 32; off; off >>= 1) s += __shfl_down(s, off);
    __shared__ float wsum[4];
    int lane = threadIdx.x & 63, wv = threadIdx.x >> 6;
    if (lane == 0) wsum[wv] = s;
    __syncthreads();
    if (threadIdx.x == 0) partials[blockIdx.x] = wsum[0] + wsum[1] + wsum[2] + wsum[3];
}

// Stage B: one wave sums the 64 partials. mean_fwd + mean_bwd = sum/ (NB*NPTS).
__global__ void reduceB_kernel(const float* __restrict__ partials, float* __restrict__ out) {
    float s = partials[threadIdx.x];
    #pragma unroll
    for (int off = 32; off; off >>= 1) s += __shfl_down(s, off);
    if (threadIdx.x == 0) out[0] = s / (float)TOTQ;
}

extern "C" void kernel_launch(void* const* d_in, const int* in_sizes, int n_in,
                              void* d_out, int out_size, void* d_ws, size_t ws_size,
                              hipStream_t stream) {
    const float* pred   = (const float*)d_in[0];
    const float* target = (const float*)d_in[1];
    char* ws = (char*)d_ws;

    float4*   ppk      = (float4*)(ws);                        // 512 KiB
    float4*   tpk      = (float4*)(ws + (size_t)TOTQ * 16);    // 512 KiB
    unsigned* mins     = (unsigned*)(ws + (size_t)2 * TOTQ * 16);        // 256 KiB
    float*    partials = (float*)(ws + (size_t)2 * TOTQ * 16 + TOTMIN * 4);
    float*    out      = (float*)d_out;

    prep_kernel<<<TOTMIN / 256, 256, 0, stream>>>(pred, target, ppk, tpk, mins);

    dim3 grid(NRC, NQC, 2 * NB);   // 8 x 64 x 4 = 2048 blocks
    nn_min_kernel<<<grid, QB, 0, stream>>>(ppk, tpk, mins);

    reduceA_kernel<<<64, 256, 0, stream>>>(mins, ppk, tpk, partials);
    reduceB_kernel<<<1, 64, 0, stream>>>(partials, out);
}

// Round 3
// 106.832 us; speedup vs baseline: 2.2132x; 1.2379x over previous
//
#include <hip/hip_runtime.h>
#include <math.h>

#define NPTS 16384
#define NB   2
#define RCH  2048            // refs per block
#define TS   512             // LDS tile (points)
#define NT   (RCH / TS)      // 4 tiles
#define NRC  (NPTS / RCH)    // 8 ref chunks
#define QPB  512             // queries per block (2 per thread)
#define NQC  (NPTS / QPB)    // 32
#define TOTQ (NB * NPTS)     // 32768
#define TOTMIN (2 * TOTQ)    // 65536

// monotone float -> uint mapping (t can be negative)
__device__ __forceinline__ unsigned ordf(float f) {
    unsigned b = __float_as_uint(f);
    return (b & 0x80000000u) ? ~b : (b | 0x80000000u);
}
__device__ __forceinline__ float deordf(unsigned u) {
    return __uint_as_float((u & 0x80000000u) ? (u ^ 0x80000000u) : ~u);
}

// Pack (x,y,z,0.5*|p|^2) for both clouds; init mins.
__global__ __launch_bounds__(256) void prep_kernel(const float* __restrict__ pred,
                                                   const float* __restrict__ target,
                                                   float4* __restrict__ ppk,
                                                   float4* __restrict__ tpk,
                                                   unsigned* __restrict__ mins) {
    int t = blockIdx.x * 256 + threadIdx.x;
    const float* src = (t < TOTQ) ? pred : target;
    float4* dst      = (t < TOTQ) ? ppk : tpk;
    int i            = (t < TOTQ) ? t : t - TOTQ;
    float x = src[3 * i], y = src[3 * i + 1], z = src[3 * i + 2];
    dst[i] = make_float4(x, y, z, 0.5f * (x * x + y * y + z * z));
    mins[t] = 0xFFFFFFFFu;
}

// Refs staged in LDS (double-buffered); each thread owns 2 queries.
// Inner: t = fma(-qz,rz, fma(-qy,ry, fma(-qx,rx, w))) ; min3 fold.
__global__ __launch_bounds__(256) void nn_min_kernel(const float4* __restrict__ ppk,
                                                     const float4* __restrict__ tpk,
                                                     unsigned* __restrict__ mins) {
    __shared__ float4 tile[2][TS];   // 16 KiB

    const int z = blockIdx.z;                 // 0..3 (fwd b0, fwd b1, bwd b0, bwd b1)
    const int b = (z < NB) ? z : z - NB;
    const float4* qarr = (z < NB) ? ppk : tpk;
    const float4* rarr = (z < NB) ? tpk : ppk;

    const int tid = threadIdx.x;
    const int qi0 = blockIdx.y * QPB + tid;   // second query at +256
    float4 q0 = qarr[b * NPTS + qi0];
    float4 q1 = qarr[b * NPTS + qi0 + 256];
    const float q0x = -q0.x, q0y = -q0.y, q0z = -q0.z;
    const float q1x = -q1.x, q1y = -q1.y, q1z = -q1.z;

    const float4* rp = rarr + b * NPTS + blockIdx.x * RCH;

    // prologue: stage tile 0
    float4 s0 = rp[tid];
    float4 s1 = rp[tid + 256];
    tile[0][tid] = s0;
    tile[0][tid + 256] = s1;
    __syncthreads();

    float m0 = INFINITY, m1 = INFINITY;
    int buf = 0;
    for (int t = 0; t < NT; ++t) {
        if (t + 1 < NT) {   // prefetch next tile into regs (VMEM in flight over compute)
            s0 = rp[(t + 1) * TS + tid];
            s1 = rp[(t + 1) * TS + tid + 256];
        }
        #pragma unroll 4
        for (int p = 0; p < TS; p += 2) {
            float4 r0 = tile[buf][p];       // broadcast ds_read_b128
            float4 r1 = tile[buf][p + 1];
            float t00 = fmaf(q0x, r0.x, r0.w); t00 = fmaf(q0y, r0.y, t00); t00 = fmaf(q0z, r0.z, t00);
            float t01 = fmaf(q0x, r1.x, r1.w); t01 = fmaf(q0y, r1.y, t01); t01 = fmaf(q0z, r1.z, t01);
            m0 = fminf(m0, fminf(t00, t01));                    // v_min3
            float t10 = fmaf(q1x, r0.x, r0.w); t10 = fmaf(q1y, r0.y, t10); t10 = fmaf(q1z, r0.z, t10);
            float t11 = fmaf(q1x, r1.x, r1.w); t11 = fmaf(q1y, r1.y, t11); t11 = fmaf(q1z, r1.z, t11);
            m1 = fminf(m1, fminf(t10, t11));
        }
        if (t + 1 < NT) {
            // safe to write buf^1 (its readers finished before previous barrier)
            tile[buf ^ 1][tid] = s0;
            tile[buf ^ 1][tid + 256] = s1;
            __syncthreads();
            buf ^= 1;
        }
    }
    atomicMin(&mins[z * NPTS + qi0], ordf(m0));
    atomicMin(&mins[z * NPTS + qi0 + 256], ordf(m1));
}

// Stage A: 64 blocks -> partial sums of sqrt(2*(w_q + t_min)).
__global__ __launch_bounds__(256) void reduceA_kernel(const unsigned* __restrict__ mins,
                                                      const float4* __restrict__ ppk,
                                                      const float4* __restrict__ tpk,
                                                      float* __restrict__ partials) {
    int base = blockIdx.x * 1024;
    float s = 0.f;
    #pragma unroll
    for (int k = 0; k < 4; ++k) {
        int t = base + k * 256 + threadIdx.x;
        float m = deordf(mins[t]);
        float w = (t < TOTQ) ? ppk[t].w : tpk[t - TOTQ].w;
        s += sqrtf(fmaxf(0.f, 2.f * (w + m)));
    }
    #pragma unroll
    for (int off = 32; off; off >>= 1) s += __shfl_down(s, off);
    __shared__ float wsum[4];
    int lane = threadIdx.x & 63, wv = threadIdx.x >> 6;
    if (lane == 0) wsum[wv] = s;
    __syncthreads();
    if (threadIdx.x == 0) partials[blockIdx.x] = wsum[0] + wsum[1] + wsum[2] + wsum[3];
}

__global__ void reduceB_kernel(const float* __restrict__ partials, float* __restrict__ out) {
    float s = partials[threadIdx.x];
    #pragma unroll
    for (int off = 32; off; off >>= 1) s += __shfl_down(s, off);
    if (threadIdx.x == 0) out[0] = s / (float)TOTQ;
}

extern "C" void kernel_launch(void* const* d_in, const int* in_sizes, int n_in,
                              void* d_out, int out_size, void* d_ws, size_t ws_size,
                              hipStream_t stream) {
    const float* pred   = (const float*)d_in[0];
    const float* target = (const float*)d_in[1];
    char* ws = (char*)d_ws;

    float4*   ppk      = (float4*)(ws);
    float4*   tpk      = (float4*)(ws + (size_t)TOTQ * 16);
    unsigned* mins     = (unsigned*)(ws + (size_t)2 * TOTQ * 16);
    float*    partials = (float*)(ws + (size_t)2 * TOTQ * 16 + (size_t)TOTMIN * 4);
    float*    out      = (float*)d_out;

    prep_kernel<<<TOTMIN / 256, 256, 0, stream>>>(pred, target, ppk, tpk, mins);

    dim3 grid(NRC, NQC, 2 * NB);   // 8 x 32 x 4 = 1024 blocks
    nn_min_kernel<<<grid, 256, 0, stream>>>(ppk, tpk, mins);

    reduceA_kernel<<<64, 256, 0, stream>>>(mins, ppk, tpk, partials);
    reduceB_kernel<<<1, 64, 0, stream>>>(partials, out);
}

// Round 4
// 91.144 us; speedup vs baseline: 2.5942x; 1.1721x over previous
//
#include <hip/hip_runtime.h>
#include <math.h>

#define NPTS 16384
#define NB   2
#define RCH  512             // refs per block = LDS tile
#define NRC  (NPTS / RCH)    // 32
#define NQ   8               // queries per thread
#define QPB  (256 * NQ)      // 2048 queries per block
#define NQC  (NPTS / QPB)    // 8
#define TOTQ (NB * NPTS)     // 32768 points per cloud
#define TOTMIN (2 * TOTQ)    // 65536 mins

typedef float f32x2 __attribute__((ext_vector_type(2)));

__device__ __forceinline__ f32x2 pk_fma(f32x2 a, f32x2 b, f32x2 c) {
    f32x2 d;
    asm("v_pk_fma_f32 %0, %1, %2, %3" : "=v"(d) : "v"(a), "v"(b), "v"(c));
    return d;
}
__device__ __forceinline__ float min3(float m, float a, float b) {
    float r;
    asm("v_min3_f32 %0, %1, %2, %3" : "=v"(r) : "v"(m), "v"(a), "v"(b));
    return r;
}

// monotone float -> uint (t can be negative)
__device__ __forceinline__ unsigned ordf(float f) {
    unsigned b = __float_as_uint(f);
    return (b & 0x80000000u) ? ~b : (b | 0x80000000u);
}
__device__ __forceinline__ float deordf(unsigned u) {
    return __uint_as_float((u & 0x80000000u) ? (u ^ 0x80000000u) : ~u);
}

// planes layout: planes[(cloud*4 + comp)*TOTQ + b*NPTS + idx], comp: 0=x 1=y 2=z 3=w(=0.5|p|^2)
__global__ __launch_bounds__(256) void prep_kernel(const float* __restrict__ pred,
                                                   const float* __restrict__ target,
                                                   float* __restrict__ planes,
                                                   unsigned* __restrict__ mins) {
    int t = blockIdx.x * 256 + threadIdx.x;      // 0..TOTMIN-1
    const float* src = (t < TOTQ) ? pred : target;
    int cloud        = (t < TOTQ) ? 0 : 1;
    int i            = (t < TOTQ) ? t : t - TOTQ;
    float x = src[3 * i], y = src[3 * i + 1], z = src[3 * i + 2];
    float* base = planes + (size_t)cloud * 4 * TOTQ;
    base[i]            = x;
    base[TOTQ + i]     = y;
    base[2 * TOTQ + i] = z;
    base[3 * TOTQ + i] = 0.5f * (x * x + y * y + z * z);
    mins[t] = 0xFFFFFFFFu;
}

// SoA LDS tile, pk_fma inner loop, 8 queries/thread.
__global__ __launch_bounds__(256, 4) void nn_min_kernel(const float* __restrict__ planes,
                                                        unsigned* __restrict__ mins) {
    __shared__ __align__(16) float lds[4][RCH];   // 8 KiB

    const int z = blockIdx.z;                 // 0: pred b0, 1: pred b1, 2: tgt b0, 3: tgt b1
    const int b = z & 1;
    const int qcloud = z >> 1;
    const int rcloud = 1 - qcloud;
    const int tid = threadIdx.x;

    // ---- stage refs (SoA float2 per thread per comp), one barrier total ----
    const int c0 = blockIdx.x * RCH;
    #pragma unroll
    for (int c = 0; c < 4; ++c) {
        const float* rp = planes + ((size_t)(rcloud * 4 + c)) * TOTQ + b * NPTS + c0;
        *(f32x2*)&lds[c][tid * 2] = *(const f32x2*)&rp[tid * 2];
    }

    // ---- load 8 queries (coalesced scalar loads from planes) ----
    const int q0 = blockIdx.y * QPB + tid;
    const float* QX = planes + ((size_t)(qcloud * 4 + 0)) * TOTQ + b * NPTS;
    const float* QY = QX + TOTQ;
    const float* QZ = QY + TOTQ;
    f32x2 nqx[NQ], nqy[NQ], nqz[NQ];
    #pragma unroll
    for (int k = 0; k < NQ; ++k) {
        float x = -QX[q0 + k * 256], y = -QY[q0 + k * 256], zz = -QZ[q0 + k * 256];
        nqx[k] = (f32x2){x, x}; nqy[k] = (f32x2){y, y}; nqz[k] = (f32x2){zz, zz};
    }

    float mA[NQ], mB[NQ];
    #pragma unroll
    for (int k = 0; k < NQ; ++k) { mA[k] = INFINITY; mB[k] = INFINITY; }

    __syncthreads();

    // ---- main loop: 4 refs/iter, 4 broadcast ds_read_b128 + 64 VALU ----
    #pragma unroll 2
    for (int p = 0; p < RCH; p += 4) {
        float4 x4 = *(const float4*)&lds[0][p];
        float4 y4 = *(const float4*)&lds[1][p];
        float4 z4 = *(const float4*)&lds[2][p];
        float4 w4 = *(const float4*)&lds[3][p];
        f32x2 x01 = {x4.x, x4.y}, x23 = {x4.z, x4.w};
        f32x2 y01 = {y4.x, y4.y}, y23 = {y4.z, y4.w};
        f32x2 z01 = {z4.x, z4.y}, z23 = {z4.z, z4.w};
        f32x2 w01 = {w4.x, w4.y}, w23 = {w4.z, w4.w};
        #pragma unroll
        for (int k = 0; k < NQ; ++k) {
            f32x2 t01 = pk_fma(nqx[k], x01, w01);
            t01 = pk_fma(nqy[k], y01, t01);
            t01 = pk_fma(nqz[k], z01, t01);
            f32x2 t23 = pk_fma(nqx[k], x23, w23);
            t23 = pk_fma(nqy[k], y23, t23);
            t23 = pk_fma(nqz[k], z23, t23);
            mA[k] = min3(mA[k], t01.x, t01.y);
            mB[k] = min3(mB[k], t23.x, t23.y);
        }
    }

    unsigned* om = mins + z * NPTS;
    #pragma unroll
    for (int k = 0; k < NQ; ++k)
        atomicMin(&om[q0 + k * 256], ordf(fminf(mA[k], mB[k])));
}

// Stage A: 64 blocks x 1024 mins -> partial sums of sqrt(2*(w_q + t_min)).
__global__ __launch_bounds__(256) void reduceA_kernel(const unsigned* __restrict__ mins,
                                                      const float* __restrict__ planes,
                                                      float* __restrict__ partials) {
    int base = blockIdx.x * 1024;
    float s = 0.f;
    #pragma unroll
    for (int k = 0; k < 4; ++k) {
        int t = base + k * 256 + threadIdx.x;
        int qcloud = t / TOTQ;              // 0: pred-query dirs, 1: target-query dirs
        int r = t - qcloud * TOTQ;          // b*NPTS + qi
        float m = deordf(mins[t]);
        float w = planes[((size_t)(qcloud * 4 + 3)) * TOTQ + r];
        s += sqrtf(fmaxf(0.f, 2.f * (w + m)));
    }
    #pragma unroll
    for (int off = 32; off; off >>= 1) s += __shfl_down(s, off);
    __shared__ float wsum[4];
    int lane = threadIdx.x & 63, wv = threadIdx.x >> 6;
    if (lane == 0) wsum[wv] = s;
    __syncthreads();
    if (threadIdx.x == 0) partials[blockIdx.x] = wsum[0] + wsum[1] + wsum[2] + wsum[3];
}

__global__ void reduceB_kernel(const float* __restrict__ partials, float* __restrict__ out) {
    float s = partials[threadIdx.x];
    #pragma unroll
    for (int off = 32; off; off >>= 1) s += __shfl_down(s, off);
    if (threadIdx.x == 0) out[0] = s / (float)TOTQ;
}

extern "C" void kernel_launch(void* const* d_in, const int* in_sizes, int n_in,
                              void* d_out, int out_size, void* d_ws, size_t ws_size,
                              hipStream_t stream) {
    const float* pred   = (const float*)d_in[0];
    const float* target = (const float*)d_in[1];
    char* ws = (char*)d_ws;

    float*    planes   = (float*)ws;                                    // 8*TOTQ floats = 1 MiB
    unsigned* mins     = (unsigned*)(ws + (size_t)8 * TOTQ * 4);        // 256 KiB
    float*    partials = (float*)(ws + (size_t)8 * TOTQ * 4 + (size_t)TOTMIN * 4);
    float*    out      = (float*)d_out;

    prep_kernel<<<TOTMIN / 256, 256, 0, stream>>>(pred, target, planes, mins);

    dim3 grid(NRC, NQC, 2 * NB);   // 32 x 8 x 4 = 1024 blocks
    nn_min_kernel<<<grid, 256, 0, stream>>>(planes, mins);

    reduceA_kernel<<<64, 256, 0, stream>>>(mins, planes, partials);
    reduceB_kernel<<<1, 64, 0, stream>>>(partials, out);
}

// Round 5
// 90.477 us; speedup vs baseline: 2.6133x; 1.0074x over previous
//
#include <hip/hip_runtime.h>
#include <math.h>

#define NPTS 16384
#define NB   2
#define RCH  512             // refs per block chunk
#define NRC  (NPTS / RCH)    // 32
#define NQ   8               // queries per thread
#define QPB  (256 * NQ)      // 2048 queries per block
#define NQC  (NPTS / QPB)    // 8
#define TOTQ (NB * NPTS)     // 32768 points per cloud
#define TOTMIN (2 * TOTQ)    // 65536 mins

typedef float f32x2 __attribute__((ext_vector_type(2)));

// a in SGPR pair (block-uniform ref components), b,c in VGPRs. 1 SGPR operand: legal VOP3P.
__device__ __forceinline__ f32x2 pk_fma_s(f32x2 as, f32x2 bv, f32x2 cv) {
    f32x2 d;
    asm("v_pk_fma_f32 %0, %1, %2, %3" : "=v"(d) : "s"(as), "v"(bv), "v"(cv));
    return d;
}
__device__ __forceinline__ float min3(float m, float a, float b) {
    float r;
    asm("v_min3_f32 %0, %1, %2, %3" : "=v"(r) : "v"(m), "v"(a), "v"(b));
    return r;
}

// monotone float -> uint (t can be negative)
__device__ __forceinline__ unsigned ordf(float f) {
    unsigned b = __float_as_uint(f);
    return (b & 0x80000000u) ? ~b : (b | 0x80000000u);
}
__device__ __forceinline__ float deordf(unsigned u) {
    return __uint_as_float((u & 0x80000000u) ? (u ^ 0x80000000u) : ~u);
}

// planes[(cloud*4 + comp)*TOTQ + b*NPTS + idx]; comp 0=x 1=y 2=z 3=w(=0.5|p|^2)
__global__ __launch_bounds__(256) void prep_kernel(const float* __restrict__ pred,
                                                   const float* __restrict__ target,
                                                   float* __restrict__ planes,
                                                   unsigned* __restrict__ mins) {
    int t = blockIdx.x * 256 + threadIdx.x;
    const float* src = (t < TOTQ) ? pred : target;
    int cloud        = (t < TOTQ) ? 0 : 1;
    int i            = (t < TOTQ) ? t : t - TOTQ;
    float x = src[3 * i], y = src[3 * i + 1], z = src[3 * i + 2];
    float* base = planes + (size_t)cloud * 4 * TOTQ;
    base[i]            = x;
    base[TOTQ + i]     = y;
    base[2 * TOTQ + i] = z;
    base[3 * TOTQ + i] = 0.5f * (x * x + y * y + z * z);
    mins[t] = 0xFFFFFFFFu;
}

// Refs streamed through SGPRs (uniform s_load_dwordx4 per SoA plane); zero LDS/DS.
__global__ __launch_bounds__(256, 4) void nn_min_kernel(const float* __restrict__ planes,
                                                        unsigned* __restrict__ mins) {
    const int z = blockIdx.z;                 // 0,1: pred-queries b0,b1 ; 2,3: target-queries
    const int b = z & 1;
    const int qcloud = z >> 1;
    const int rcloud = 1 - qcloud;
    const int tid = threadIdx.x;

    // uniform SoA ref plane pointers for this chunk
    const int c0 = blockIdx.x * RCH;
    const float* __restrict__ RX = planes + ((size_t)(rcloud * 4 + 0)) * TOTQ + b * NPTS + c0;
    const float* __restrict__ RY = RX + TOTQ;
    const float* __restrict__ RZ = RY + TOTQ;
    const float* __restrict__ RW = RZ + TOTQ;

    // 8 queries per thread, stored as negated broadcast pairs
    const int q0 = blockIdx.y * QPB + tid;
    const float* __restrict__ QX = planes + ((size_t)(qcloud * 4 + 0)) * TOTQ + b * NPTS;
    const float* __restrict__ QY = QX + TOTQ;
    const float* __restrict__ QZ = QY + TOTQ;
    f32x2 nqx[NQ], nqy[NQ], nqz[NQ];
    #pragma unroll
    for (int k = 0; k < NQ; ++k) {
        float x = -QX[q0 + k * 256], y = -QY[q0 + k * 256], zz = -QZ[q0 + k * 256];
        nqx[k] = (f32x2){x, x}; nqy[k] = (f32x2){y, y}; nqz[k] = (f32x2){zz, zz};
    }

    float mA[NQ], mB[NQ];
    #pragma unroll
    for (int k = 0; k < NQ; ++k) { mA[k] = INFINITY; mB[k] = INFINITY; }

    // rotate: load batch j+4 while computing batch j (s_loads, scalar pipe)
    float4 cx = *(const float4*)&RX[0];
    float4 cy = *(const float4*)&RY[0];
    float4 cz = *(const float4*)&RZ[0];
    float4 cw = *(const float4*)&RW[0];

    for (int p = 0; p < RCH; p += 4) {
        float4 nx, ny, nz, nw;
        if (p + 4 < RCH) {
            nx = *(const float4*)&RX[p + 4];
            ny = *(const float4*)&RY[p + 4];
            nz = *(const float4*)&RZ[p + 4];
            nw = *(const float4*)&RW[p + 4];
        }
        f32x2 x01 = {cx.x, cx.y}, x23 = {cx.z, cx.w};
        f32x2 y01 = {cy.x, cy.y}, y23 = {cy.z, cy.w};
        f32x2 z01 = {cz.x, cz.y}, z23 = {cz.z, cz.w};
        f32x2 w01 = {cw.x, cw.y}, w23 = {cw.z, cw.w};   // -> 4 v_mov to VGPR pairs
        #pragma unroll
        for (int k = 0; k < NQ; ++k) {
            f32x2 t01 = pk_fma_s(x01, nqx[k], w01);
            t01 = pk_fma_s(y01, nqy[k], t01);
            t01 = pk_fma_s(z01, nqz[k], t01);
            f32x2 t23 = pk_fma_s(x23, nqx[k], w23);
            t23 = pk_fma_s(y23, nqy[k], t23);
            t23 = pk_fma_s(z23, nqz[k], t23);
            mA[k] = min3(mA[k], t01.x, t01.y);
            mB[k] = min3(mB[k], t23.x, t23.y);
        }
        cx = nx; cy = ny; cz = nz; cw = nw;
    }

    unsigned* om = mins + z * NPTS;
    #pragma unroll
    for (int k = 0; k < NQ; ++k)
        atomicMin(&om[q0 + k * 256], ordf(fminf(mA[k], mB[k])));
}

// Stage A: 64 blocks x 1024 mins -> partial sums of sqrt(2*(w_q + t_min)).
__global__ __launch_bounds__(256) void reduceA_kernel(const unsigned* __restrict__ mins,
                                                      const float* __restrict__ planes,
                                                      float* __restrict__ partials) {
    int base = blockIdx.x * 1024;
    float s = 0.f;
    #pragma unroll
    for (int k = 0; k < 4; ++k) {
        int t = base + k * 256 + threadIdx.x;
        int qcloud = t / TOTQ;
        int r = t - qcloud * TOTQ;          // b*NPTS + qi
        float m = deordf(mins[t]);
        float w = planes[((size_t)(qcloud * 4 + 3)) * TOTQ + r];
        s += sqrtf(fmaxf(0.f, 2.f * (w + m)));
    }
    #pragma unroll
    for (int off = 32; off; off >>= 1) s += __shfl_down(s, off);
    __shared__ float wsum[4];
    int lane = threadIdx.x & 63, wv = threadIdx.x >> 6;
    if (lane == 0) wsum[wv] = s;
    __syncthreads();
    if (threadIdx.x == 0) partials[blockIdx.x] = wsum[0] + wsum[1] + wsum[2] + wsum[3];
}

__global__ void reduceB_kernel(const float* __restrict__ partials, float* __restrict__ out) {
    float s = partials[threadIdx.x];
    #pragma unroll
    for (int off = 32; off; off >>= 1) s += __shfl_down(s, off);
    if (threadIdx.x == 0) out[0] = s / (float)TOTQ;
}

extern "C" void kernel_launch(void* const* d_in, const int* in_sizes, int n_in,
                              void* d_out, int out_size, void* d_ws, size_t ws_size,
                              hipStream_t stream) {
    const float* pred   = (const float*)d_in[0];
    const float* target = (const float*)d_in[1];
    char* ws = (char*)d_ws;

    float*    planes   = (float*)ws;                                    // 1 MiB SoA
    unsigned* mins     = (unsigned*)(ws + (size_t)8 * TOTQ * 4);        // 256 KiB
    float*    partials = (float*)(ws + (size_t)8 * TOTQ * 4 + (size_t)TOTMIN * 4);
    float*    out      = (float*)d_out;

    prep_kernel<<<TOTMIN / 256, 256, 0, stream>>>(pred, target, planes, mins);

    dim3 grid(NRC, NQC, 2 * NB);   // 32 x 8 x 4 = 1024 blocks
    nn_min_kernel<<<grid, 256, 0, stream>>>(planes, mins);

    reduceA_kernel<<<64, 256, 0, stream>>>(mins, planes, partials);
    reduceB_kernel<<<1, 64, 0, stream>>>(partials, out);
}

// Round 6
// 83.934 us; speedup vs baseline: 2.8170x; 1.0780x over previous
//
#include <hip/hip_runtime.h>
#include <math.h>

#define NPTS 16384
#define NB   2
#define RCH  256             // refs per block chunk
#define NRC  (NPTS / RCH)    // 64
#define NQ   8               // queries per thread
#define QPB  (256 * NQ)      // 2048 queries per block
#define NQC  (NPTS / QPB)    // 8
#define TOTQ (NB * NPTS)     // 32768 points per cloud
#define TOTMIN (2 * TOTQ)    // 65536 mins

typedef float f32x2 __attribute__((ext_vector_type(2)));

// d = a*b + c ; a = block-uniform ref pair in SGPRs (the one legal SGPR operand)
__device__ __forceinline__ f32x2 pk_fma_s(f32x2 as, f32x2 bv, f32x2 cv) {
    f32x2 d;
    asm("v_pk_fma_f32 %0, %1, %2, %3" : "=v"(d) : "s"(as), "v"(bv), "v"(cv));
    return d;
}
__device__ __forceinline__ float min3(float m, float a, float b) {
    float r;
    asm("v_min3_f32 %0, %1, %2, %3" : "=v"(r) : "v"(m), "v"(a), "v"(b));
    return r;
}

// monotone float -> uint (values can be negative)
__device__ __forceinline__ unsigned ordf(float f) {
    unsigned b = __float_as_uint(f);
    return (b & 0x80000000u) ? ~b : (b | 0x80000000u);
}
__device__ __forceinline__ float deordf(unsigned u) {
    return __uint_as_float((u & 0x80000000u) ? (u ^ 0x80000000u) : ~u);
}

// planes[(cloud*4 + comp)*TOTQ + b*NPTS + idx]; comp 0=x 1=y 2=z 3=w(=0.5|p|^2)
__global__ __launch_bounds__(256) void prep_kernel(const float* __restrict__ pred,
                                                   const float* __restrict__ target,
                                                   float* __restrict__ planes,
                                                   unsigned* __restrict__ mins) {
    int t = blockIdx.x * 256 + threadIdx.x;
    const float* src = (t < TOTQ) ? pred : target;
    int cloud        = (t < TOTQ) ? 0 : 1;
    int i            = (t < TOTQ) ? t : t - TOTQ;
    float x = src[3 * i], y = src[3 * i + 1], z = src[3 * i + 2];
    float* base = planes + (size_t)cloud * 4 * TOTQ;
    base[i]            = x;
    base[TOTQ + i]     = y;
    base[2 * TOTQ + i] = z;
    base[3 * TOTQ + i] = 0.5f * (x * x + y * y + z * z);
    mins[t] = 0xFFFFFFFFu;
}

// Refs streamed through SGPRs; query broadcast pairs pinned in VGPRs (asm-opaque).
__global__ __launch_bounds__(256, 4) void nn_min_kernel(const float* __restrict__ planes,
                                                        unsigned* __restrict__ mins) {
    const int z = blockIdx.z;                 // 0,1: pred-queries b0,b1 ; 2,3: target-queries
    const int b = z & 1;
    const int qcloud = z >> 1;
    const int rcloud = 1 - qcloud;
    const int tid = threadIdx.x;

    // uniform SoA ref plane pointers for this chunk (scalarized loads)
    const int c0 = blockIdx.x * RCH;
    const float* __restrict__ RX = planes + ((size_t)(rcloud * 4 + 0)) * TOTQ + b * NPTS + c0;
    const float* __restrict__ RY = RX + TOTQ;
    const float* __restrict__ RZ = RY + TOTQ;
    const float* __restrict__ RW = RZ + TOTQ;

    // 8 queries per thread as negated broadcast pairs, made asm-opaque so the
    // register allocator CANNOT rematerialize them inside the loop.
    const int q0 = blockIdx.y * QPB + tid;
    const float* __restrict__ QX = planes + ((size_t)(qcloud * 4 + 0)) * TOTQ + b * NPTS;
    const float* __restrict__ QY = QX + TOTQ;
    const float* __restrict__ QZ = QY + TOTQ;
    f32x2 nqx[NQ], nqy[NQ], nqz[NQ];
    #pragma unroll
    for (int k = 0; k < NQ; ++k) {
        float x = -QX[q0 + k * 256], y = -QY[q0 + k * 256], zz = -QZ[q0 + k * 256];
        f32x2 tx = {x, x}, ty = {y, y}, tz = {zz, zz};
        asm("" : "+v"(tx), "+v"(ty), "+v"(tz));   // opaque: must stay in VGPRs
        nqx[k] = tx; nqy[k] = ty; nqz[k] = tz;
    }

    float mA[NQ], mB[NQ];
    #pragma unroll
    for (int k = 0; k < NQ; ++k) { mA[k] = INFINITY; mB[k] = INFINITY; }

#define BATCH(sx, sy, sz, sw)                                              \
    {                                                                      \
        f32x2 x01 = {sx.x, sx.y}, x23 = {sx.z, sx.w};                      \
        f32x2 y01 = {sy.x, sy.y}, y23 = {sy.z, sy.w};                      \
        f32x2 z01 = {sz.x, sz.y}, z23 = {sz.z, sz.w};                      \
        f32x2 w01 = {sw.x, sw.y}, w23 = {sw.z, sw.w};                      \
        _Pragma("unroll")                                                  \
        for (int k = 0; k < NQ; ++k) {                                     \
            f32x2 t01 = pk_fma_s(x01, nqx[k], w01);                        \
            t01 = pk_fma_s(y01, nqy[k], t01);                              \
            t01 = pk_fma_s(z01, nqz[k], t01);                              \
            f32x2 t23 = pk_fma_s(x23, nqx[k], w23);                        \
            t23 = pk_fma_s(y23, nqy[k], t23);                              \
            t23 = pk_fma_s(z23, nqz[k], t23);                              \
            mA[k] = min3(mA[k], t01.x, t01.y);                             \
            mB[k] = min3(mB[k], t23.x, t23.y);                             \
        }                                                                  \
    }

    // 2-batch-deep scalar-load pipeline: prefetch p+8 while computing p, p+4
    float4 ax = *(const float4*)&RX[0], ay = *(const float4*)&RY[0];
    float4 az = *(const float4*)&RZ[0], aw = *(const float4*)&RW[0];
    float4 bx = *(const float4*)&RX[4], by = *(const float4*)&RY[4];
    float4 bz = *(const float4*)&RZ[4], bw = *(const float4*)&RW[4];

    for (int p = 0; p < RCH; p += 8) {
        const int pa = (p + 8 < RCH) ? p + 8 : p;      // clamped prefetch (uniform)
        const int pb = pa + 4;
        float4 nax = *(const float4*)&RX[pa], nay = *(const float4*)&RY[pa];
        float4 naz = *(const float4*)&RZ[pa], naw = *(const float4*)&RW[pa];
        float4 nbx = *(const float4*)&RX[pb], nby = *(const float4*)&RY[pb];
        float4 nbz = *(const float4*)&RZ[pb], nbw = *(const float4*)&RW[pb];
        BATCH(ax, ay, az, aw);
        BATCH(bx, by, bz, bw);
        ax = nax; ay = nay; az = naz; aw = naw;
        bx = nbx; by = nby; bz = nbz; bw = nbw;
    }
#undef BATCH

    unsigned* om = mins + z * NPTS;
    #pragma unroll
    for (int k = 0; k < NQ; ++k)
        atomicMin(&om[q0 + k * 256], ordf(fminf(mA[k], mB[k])));
}

// Stage A: 64 blocks x 1024 mins -> partial sums of sqrt(2*(w_q + t_min)).
__global__ __launch_bounds__(256) void reduceA_kernel(const unsigned* __restrict__ mins,
                                                      const float* __restrict__ planes,
                                                      float* __restrict__ partials) {
    int base = blockIdx.x * 1024;
    float s = 0.f;
    #pragma unroll
    for (int k = 0; k < 4; ++k) {
        int t = base + k * 256 + threadIdx.x;
        int qcloud = t / TOTQ;
        int r = t - qcloud * TOTQ;          // b*NPTS + qi
        float m = deordf(mins[t]);
        float w = planes[((size_t)(qcloud * 4 + 3)) * TOTQ + r];
        s += sqrtf(fmaxf(0.f, 2.f * (w + m)));
    }
    #pragma unroll
    for (int off = 32; off; off >>= 1) s += __shfl_down(s, off);
    __shared__ float wsum[4];
    int lane = threadIdx.x & 63, wv = threadIdx.x >> 6;
    if (lane == 0) wsum[wv] = s;
    __syncthreads();
    if (threadIdx.x == 0) partials[blockIdx.x] = wsum[0] + wsum[1] + wsum[2] + wsum[3];
}

__global__ void reduceB_kernel(const float* __restrict__ partials, float* __restrict__ out) {
    float s = partials[threadIdx.x];
    #pragma unroll
    for (int off = 32; off; off >>= 1) s += __shfl_down(s, off);
    if (threadIdx.x == 0) out[0] = s / (float)TOTQ;
}

extern "C" void kernel_launch(void* const* d_in, const int* in_sizes, int n_in,
                              void* d_out, int out_size, void* d_ws, size_t ws_size,
                              hipStream_t stream) {
    const float* pred   = (const float*)d_in[0];
    const float* target = (const float*)d_in[1];
    char* ws = (char*)d_ws;

    float*    planes   = (float*)ws;                                    // 1 MiB SoA
    unsigned* mins     = (unsigned*)(ws + (size_t)8 * TOTQ * 4);        // 256 KiB
    float*    partials = (float*)(ws + (size_t)8 * TOTQ * 4 + (size_t)TOTMIN * 4);
    float*    out      = (float*)d_out;

    prep_kernel<<<TOTMIN / 256, 256, 0, stream>>>(pred, target, planes, mins);

    dim3 grid(NRC, NQC, 2 * NB);   // 64 x 8 x 4 = 2048 blocks
    nn_min_kernel<<<grid, 256, 0, stream>>>(planes, mins);

    reduceA_kernel<<<64, 256, 0, stream>>>(mins, planes, partials);
    reduceB_kernel<<<1, 64, 0, stream>>>(partials, out);
}

// Round 7
// 57.421 us; speedup vs baseline: 4.1177x; 1.4617x over previous
//
#include <hip/hip_runtime.h>
#include <math.h>

#define NPTS 16384
#define NB   2
#define RCH  1024               // refs per block (LDS tile), 32 KiB
#define NRC  (NPTS / RCH)       // 16
#define TILES (RCH / 32)        // 32 mfma ref-tiles per block
#define QPB  512                // queries per block: 4 waves * 4 frags * 32
#define NQC  (NPTS / QPB)       // 32
#define TOTQ (NB * NPTS)        // 32768
#define TOTMIN (2 * TOTQ)       // 65536

typedef short bf16x8 __attribute__((ext_vector_type(8)));
typedef float f32x16 __attribute__((ext_vector_type(16)));

__device__ __forceinline__ float min3(float m, float a, float b) {
    float r;
    asm("v_min3_f32 %0, %1, %2, %3" : "=v"(r) : "v"(m), "v"(a), "v"(b));
    return r;
}
// monotone float <-> uint (t can be negative)
__device__ __forceinline__ unsigned ordf(float f) {
    unsigned b = __float_as_uint(f);
    return (b & 0x80000000u) ? ~b : (b | 0x80000000u);
}
__device__ __forceinline__ float deordf(unsigned u) {
    return __uint_as_float((u & 0x80000000u) ? (u ^ 0x80000000u) : ~u);
}
// bf16 round-to-nearest-even, hand-rolled (no header dependence)
__device__ __forceinline__ unsigned short bfr(float v) {
    unsigned u = __float_as_uint(v);
    u += 0x7FFFu + ((u >> 16) & 1u);
    return (unsigned short)(u >> 16);
}
__device__ __forceinline__ float ubf(unsigned short h) {
    return __uint_as_float(((unsigned)h) << 16);
}

// K-slot assignment (11 of 16 used):
//  k:      0     1     2     3     4     5     6     7  |  8     9    10   11..15
//  A(ref): rhx   rlx   rhx   rhy   rly   rhy   rhz   rlz|  rhz   wh   wl   0
//  B(qry): -qhx  -qhx  -qlx  -qhy  -qhy  -qly  -qhz  -qhz| -qlz  1.0  1.0  0
// => C = 0.5|r|^2 - q.r  (missing only ql*rl terms, ~2^-18 rel)
__global__ __launch_bounds__(256) void prep_kernel(const float* __restrict__ pred,
                                                   const float* __restrict__ target,
                                                   unsigned short* __restrict__ panel,
                                                   unsigned short* __restrict__ qpack,
                                                   float* __restrict__ wq,
                                                   unsigned* __restrict__ mins) {
    int t = blockIdx.x * 256 + threadIdx.x;      // 0..65535
    int cloud = t >> 15, r = t & 32767, b = r >> 14, i = r & 16383;
    const float* src = cloud ? target : pred;
    float x = src[(b * NPTS + i) * 3 + 0];
    float y = src[(b * NPTS + i) * 3 + 1];
    float zz = src[(b * NPTS + i) * 3 + 2];
    float w = 0.5f * (x * x + y * y + zz * zz);

    unsigned short hx = bfr(x),  lx = bfr(x - ubf(hx));
    unsigned short hy = bfr(y),  ly = bfr(y - ubf(hy));
    unsigned short hz = bfr(zz), lz = bfr(zz - ubf(hz));
    unsigned short hw = bfr(w),  lw = bfr(w - ubf(hw));

    const int slot = cloud * 2 + b;              // matches z = qcloud*2 + b

    // A-panel: ref-major, 32B/ref, LDS-linear (chunk l of tile <-> lane l)
    unsigned short* pp = panel + ((size_t)slot << 18) + (size_t)(i >> 5) * 512 + (size_t)(i & 31) * 8;
    uint4 k0, k1;
    k0.x = hx | ((unsigned)lx << 16);
    k0.y = hx | ((unsigned)hy << 16);
    k0.z = ly | ((unsigned)hy << 16);
    k0.w = hz | ((unsigned)lz << 16);
    *(uint4*)pp = k0;
    k1.x = hz | ((unsigned)hw << 16);
    k1.y = lw;
    k1.z = 0; k1.w = 0;
    *(uint4*)(pp + 256) = k1;                    // kgroup1 half-tile at +512B

    // B-pack: 32B/query, negated split (negation = sign flip, exact)
    const unsigned short S = 0x8000u, ONE = 0x3F80u;
    unsigned short nhx = hx ^ S, nlx = lx ^ S, nhy = hy ^ S, nly = ly ^ S, nhz = hz ^ S, nlz = lz ^ S;
    unsigned short* qp = qpack + ((size_t)slot << 18) + (size_t)i * 16;
    uint4 qlo, qhi;
    qlo.x = nhx | ((unsigned)nhx << 16);
    qlo.y = nlx | ((unsigned)nhy << 16);
    qlo.z = nhy | ((unsigned)nly << 16);
    qlo.w = nhz | ((unsigned)nhz << 16);
    qhi.x = nlz | ((unsigned)ONE << 16);
    qhi.y = ONE;
    qhi.z = 0; qhi.w = 0;
    *(uint4*)qp = qlo;
    *(uint4*)(qp + 8) = qhi;

    wq[(slot << 14) | i] = w;                    // 0.5|q|^2 for the epilogue
    mins[(slot << 14) | i] = 0xFFFFFFFFu;
}

__global__ __launch_bounds__(256) void nn_min_kernel(const unsigned short* __restrict__ panel,
                                                     const unsigned short* __restrict__ qpack,
                                                     unsigned* __restrict__ mins) {
    __shared__ __attribute__((aligned(16))) unsigned short lds_s[RCH * 16];  // 32 KiB

    const int z = blockIdx.z, b = z & 1, qc = z >> 1, rc = 1 - qc;
    const int tid = threadIdx.x, ln = tid & 63, wv = tid >> 6;

    // ---- stage ref panel chunk -> LDS (layout already LDS-linear) ----
    const unsigned short* pbase = panel + (((size_t)(rc * 2 + b)) << 18) + (size_t)blockIdx.x * (RCH * 16);
    uint4 st0 = *(const uint4*)(pbase + (0 * 256 + tid) * 8);
    uint4 st1 = *(const uint4*)(pbase + (1 * 256 + tid) * 8);
    uint4 st2 = *(const uint4*)(pbase + (2 * 256 + tid) * 8);
    uint4 st3 = *(const uint4*)(pbase + (3 * 256 + tid) * 8);
    uint4 st4 = *(const uint4*)(pbase + (4 * 256 + tid) * 8);
    uint4 st5 = *(const uint4*)(pbase + (5 * 256 + tid) * 8);
    uint4 st6 = *(const uint4*)(pbase + (6 * 256 + tid) * 8);
    uint4 st7 = *(const uint4*)(pbase + (7 * 256 + tid) * 8);

    // ---- B fragments: 4 query-frags of 32 queries per wave ----
    const int qbase = blockIdx.y * QPB;
    const unsigned short* qb = qpack + (((size_t)(qc * 2 + b)) << 18);
    const int qcol = ln & 31, khalf = (ln >> 5) * 8;
    bf16x8 B0 = *(const bf16x8*)(qb + (size_t)(qbase + (wv * 4 + 0) * 32 + qcol) * 16 + khalf);
    bf16x8 B1 = *(const bf16x8*)(qb + (size_t)(qbase + (wv * 4 + 1) * 32 + qcol) * 16 + khalf);
    bf16x8 B2 = *(const bf16x8*)(qb + (size_t)(qbase + (wv * 4 + 2) * 32 + qcol) * 16 + khalf);
    bf16x8 B3 = *(const bf16x8*)(qb + (size_t)(qbase + (wv * 4 + 3) * 32 + qcol) * 16 + khalf);

    *(uint4*)&lds_s[(0 * 256 + tid) * 8] = st0;
    *(uint4*)&lds_s[(1 * 256 + tid) * 8] = st1;
    *(uint4*)&lds_s[(2 * 256 + tid) * 8] = st2;
    *(uint4*)&lds_s[(3 * 256 + tid) * 8] = st3;
    *(uint4*)&lds_s[(4 * 256 + tid) * 8] = st4;
    *(uint4*)&lds_s[(5 * 256 + tid) * 8] = st5;
    *(uint4*)&lds_s[(6 * 256 + tid) * 8] = st6;
    *(uint4*)&lds_s[(7 * 256 + tid) * 8] = st7;
    __syncthreads();

    f32x16 cz = {0.f, 0.f, 0.f, 0.f, 0.f, 0.f, 0.f, 0.f,
                 0.f, 0.f, 0.f, 0.f, 0.f, 0.f, 0.f, 0.f};   // persistent zero C
    float mA0 = INFINITY, mB0 = INFINITY, mA1 = INFINITY, mB1 = INFINITY;
    float mA2 = INFINITY, mB2 = INFINITY, mA3 = INFINITY, mB3 = INFINITY;

#define FOLD(mA, mB)                                      \
    mA = min3(mA, d[0], d[1]);   mB = min3(mB, d[2], d[3]);   \
    mA = min3(mA, d[4], d[5]);   mB = min3(mB, d[6], d[7]);   \
    mA = min3(mA, d[8], d[9]);   mB = min3(mB, d[10], d[11]); \
    mA = min3(mA, d[12], d[13]); mB = min3(mB, d[14], d[15]);

    #pragma unroll 4
    for (int t = 0; t < TILES; ++t) {
        bf16x8 a = *(const bf16x8*)&lds_s[t * 512 + ln * 8];   // ds_read_b128
        {
            f32x16 d = __builtin_amdgcn_mfma_f32_32x32x16_bf16(a, B0, cz, 0, 0, 0);
            FOLD(mA0, mB0)
        }
        {
            f32x16 d = __builtin_amdgcn_mfma_f32_32x32x16_bf16(a, B1, cz, 0, 0, 0);
            FOLD(mA1, mB1)
        }
        {
            f32x16 d = __builtin_amdgcn_mfma_f32_32x32x16_bf16(a, B2, cz, 0, 0, 0);
            FOLD(mA2, mB2)
        }
        {
            f32x16 d = __builtin_amdgcn_mfma_f32_32x32x16_bf16(a, B3, cz, 0, 0, 0);
            FOLD(mA3, mB3)
        }
    }
#undef FOLD

    unsigned* om = mins + ((size_t)z << 14) + qbase;
    atomicMin(&om[(wv * 4 + 0) * 32 + qcol], ordf(fminf(mA0, mB0)));
    atomicMin(&om[(wv * 4 + 1) * 32 + qcol], ordf(fminf(mA1, mB1)));
    atomicMin(&om[(wv * 4 + 2) * 32 + qcol], ordf(fminf(mA2, mB2)));
    atomicMin(&om[(wv * 4 + 3) * 32 + qcol], ordf(fminf(mA3, mB3)));
}

// d = sqrt(max(0, 2*(0.5|q|^2 + t_min)))
__global__ __launch_bounds__(256) void reduceA_kernel(const unsigned* __restrict__ mins,
                                                      const float* __restrict__ wq,
                                                      float* __restrict__ partials) {
    int base = blockIdx.x * 1024;
    float s = 0.f;
    #pragma unroll
    for (int k = 0; k < 4; ++k) {
        int t = base + k * 256 + threadIdx.x;
        float m = deordf(mins[t]);
        s += sqrtf(fmaxf(0.f, 2.f * (wq[t] + m)));
    }
    #pragma unroll
    for (int off = 32; off; off >>= 1) s += __shfl_down(s, off);
    __shared__ float wsum[4];
    int lane = threadIdx.x & 63, wv = threadIdx.x >> 6;
    if (lane == 0) wsum[wv] = s;
    __syncthreads();
    if (threadIdx.x == 0) partials[blockIdx.x] = wsum[0] + wsum[1] + wsum[2] + wsum[3];
}

__global__ void reduceB_kernel(const float* __restrict__ partials, float* __restrict__ out) {
    float s = partials[threadIdx.x];
    #pragma unroll
    for (int off = 32; off; off >>= 1) s += __shfl_down(s, off);
    if (threadIdx.x == 0) out[0] = s / (float)TOTQ;
}

extern "C" void kernel_launch(void* const* d_in, const int* in_sizes, int n_in,
                              void* d_out, int out_size, void* d_ws, size_t ws_size,
                              hipStream_t stream) {
    const float* pred   = (const float*)d_in[0];
    const float* target = (const float*)d_in[1];
    char* ws = (char*)d_ws;

    // ws layout: panel 2MB | qpack 2MB | wq 256KB | mins 256KB | partials
    unsigned short* panel = (unsigned short*)ws;
    unsigned short* qpack = (unsigned short*)(ws + (size_t)2 * 1024 * 1024);
    float*          wq    = (float*)(ws + (size_t)4 * 1024 * 1024);
    unsigned*       mins  = (unsigned*)(ws + (size_t)4 * 1024 * 1024 + 256 * 1024);
    float*       partials = (float*)(ws + (size_t)4 * 1024 * 1024 + 512 * 1024);
    float* out = (float*)d_out;

    prep_kernel<<<TOTMIN / 256, 256, 0, stream>>>(pred, target, panel, qpack, wq, mins);

    dim3 grid(NRC, NQC, 2 * NB);   // 16 x 32 x 4 = 2048 blocks
    nn_min_kernel<<<grid, 256, 0, stream>>>(panel, qpack, mins);

    reduceA_kernel<<<64, 256, 0, stream>>>(mins, wq, partials);
    reduceB_kernel<<<1, 64, 0, stream>>>(partials, out);
}

// Round 8
// 45.459 us; speedup vs baseline: 5.2012x; 1.2631x over previous
//
#include <hip/hip_runtime.h>
#include <math.h>

#define NPTS 16384
#define NB   2
#define RCH  1024               // refs per block (LDS tile), 32 KiB
#define NRC  (NPTS / RCH)       // 16
#define TILES (RCH / 32)        // 32 mfma ref-tiles per block
#define QPB  512                // queries per block: 4 waves * 4 frags * 32
#define NQC  (NPTS / QPB)       // 32
#define TOTQ (NB * NPTS)        // 32768
#define TOTMIN (2 * TOTQ)       // 65536

typedef short bf16x8 __attribute__((ext_vector_type(8)));
typedef float f32x16 __attribute__((ext_vector_type(16)));

__device__ __forceinline__ float min3(float m, float a, float b) {
    float r;
    asm("v_min3_f32 %0, %1, %2, %3" : "=v"(r) : "v"(m), "v"(a), "v"(b));
    return r;
}
// monotone float <-> uint (t can be negative)
__device__ __forceinline__ unsigned ordf(float f) {
    unsigned b = __float_as_uint(f);
    return (b & 0x80000000u) ? ~b : (b | 0x80000000u);
}
__device__ __forceinline__ float deordf(unsigned u) {
    return __uint_as_float((u & 0x80000000u) ? (u ^ 0x80000000u) : ~u);
}
// bf16 round-to-nearest-even
__device__ __forceinline__ unsigned short bfr(float v) {
    unsigned u = __float_as_uint(v);
    u += 0x7FFFu + ((u >> 16) & 1u);
    return (unsigned short)(u >> 16);
}
__device__ __forceinline__ float ubf(unsigned short h) {
    return __uint_as_float(((unsigned)h) << 16);
}

// 4 MFMAs in one asm block: all operands pinned to VGPRs (gfx950 unified RF).
// Early-clobber D tuples; in-order issue => d0 has 24cyc of MFMA gap, d3 has
// 16cyc of s_nop >= 11 wait-states (8-pass MFMA vdst->VALU read hazard).
__device__ __forceinline__ void mfma4(bf16x8 a, bf16x8 b0, bf16x8 b1, bf16x8 b2, bf16x8 b3,
                                      const f32x16& cz,
                                      f32x16& d0, f32x16& d1, f32x16& d2, f32x16& d3) {
    asm("v_mfma_f32_32x32x16_bf16 %0, %4, %5, %9\n\t"
        "v_mfma_f32_32x32x16_bf16 %1, %4, %6, %9\n\t"
        "v_mfma_f32_32x32x16_bf16 %2, %4, %7, %9\n\t"
        "v_mfma_f32_32x32x16_bf16 %3, %4, %8, %9\n\t"
        "s_nop 7\n\t"
        "s_nop 7"
        : "=&v"(d0), "=&v"(d1), "=&v"(d2), "=&v"(d3)
        : "v"(a), "v"(b0), "v"(b1), "v"(b2), "v"(b3), "v"(cz));
}

// K-slot assignment (11 of 16 used):
//  k:      0     1     2     3     4     5     6     7  |  8     9    10   11..15
//  A(ref): rhx   rlx   rhx   rhy   rly   rhy   rhz   rlz|  rhz   wh   wl   0
//  B(qry): -qhx  -qhx  -qlx  -qhy  -qhy  -qly  -qhz  -qhz| -qlz  1.0  1.0  0
// => C = 0.5|r|^2 - q.r
__global__ __launch_bounds__(256) void prep_kernel(const float* __restrict__ pred,
                                                   const float* __restrict__ target,
                                                   unsigned short* __restrict__ panel,
                                                   unsigned short* __restrict__ qpack,
                                                   float* __restrict__ wq,
                                                   unsigned* __restrict__ mins) {
    int t = blockIdx.x * 256 + threadIdx.x;      // 0..65535
    int cloud = t >> 15, r = t & 32767, b = r >> 14, i = r & 16383;
    const float* src = cloud ? target : pred;
    float x = src[(b * NPTS + i) * 3 + 0];
    float y = src[(b * NPTS + i) * 3 + 1];
    float zz = src[(b * NPTS + i) * 3 + 2];
    float w = 0.5f * (x * x + y * y + zz * zz);

    unsigned short hx = bfr(x),  lx = bfr(x - ubf(hx));
    unsigned short hy = bfr(y),  ly = bfr(y - ubf(hy));
    unsigned short hz = bfr(zz), lz = bfr(zz - ubf(hz));
    unsigned short hw = bfr(w),  lw = bfr(w - ubf(hw));

    const int slot = cloud * 2 + b;

    // A-panel: ref-major, 32B/ref, LDS-linear
    unsigned short* pp = panel + ((size_t)slot << 18) + (size_t)(i >> 5) * 512 + (size_t)(i & 31) * 8;
    uint4 k0, k1;
    k0.x = hx | ((unsigned)lx << 16);
    k0.y = hx | ((unsigned)hy << 16);
    k0.z = ly | ((unsigned)hy << 16);
    k0.w = hz | ((unsigned)lz << 16);
    *(uint4*)pp = k0;
    k1.x = hz | ((unsigned)hw << 16);
    k1.y = lw;
    k1.z = 0; k1.w = 0;
    *(uint4*)(pp + 256) = k1;

    // B-pack: 32B/query, negated split
    const unsigned short S = 0x8000u, ONE = 0x3F80u;
    unsigned short nhx = hx ^ S, nlx = lx ^ S, nhy = hy ^ S, nly = ly ^ S, nhz = hz ^ S, nlz = lz ^ S;
    unsigned short* qp = qpack + ((size_t)slot << 18) + (size_t)i * 16;
    uint4 qlo, qhi;
    qlo.x = nhx | ((unsigned)nhx << 16);
    qlo.y = nlx | ((unsigned)nhy << 16);
    qlo.z = nhy | ((unsigned)nly << 16);
    qlo.w = nhz | ((unsigned)nhz << 16);
    qhi.x = nlz | ((unsigned)ONE << 16);
    qhi.y = ONE;
    qhi.z = 0; qhi.w = 0;
    *(uint4*)qp = qlo;
    *(uint4*)(qp + 8) = qhi;

    wq[(slot << 14) | i] = w;
    mins[(slot << 14) | i] = 0xFFFFFFFFu;
}

__global__ __launch_bounds__(256) void nn_min_kernel(const unsigned short* __restrict__ panel,
                                                     const unsigned short* __restrict__ qpack,
                                                     unsigned* __restrict__ mins) {
    __shared__ __attribute__((aligned(16))) unsigned short lds_s[RCH * 16];  // 32 KiB

    const int z = blockIdx.z, b = z & 1, qc = z >> 1, rc = 1 - qc;
    const int tid = threadIdx.x, ln = tid & 63, wv = tid >> 6;

    // ---- stage ref panel chunk -> LDS ----
    const unsigned short* pbase = panel + (((size_t)(rc * 2 + b)) << 18) + (size_t)blockIdx.x * (RCH * 16);
    uint4 st0 = *(const uint4*)(pbase + (0 * 256 + tid) * 8);
    uint4 st1 = *(const uint4*)(pbase + (1 * 256 + tid) * 8);
    uint4 st2 = *(const uint4*)(pbase + (2 * 256 + tid) * 8);
    uint4 st3 = *(const uint4*)(pbase + (3 * 256 + tid) * 8);
    uint4 st4 = *(const uint4*)(pbase + (4 * 256 + tid) * 8);
    uint4 st5 = *(const uint4*)(pbase + (5 * 256 + tid) * 8);
    uint4 st6 = *(const uint4*)(pbase + (6 * 256 + tid) * 8);
    uint4 st7 = *(const uint4*)(pbase + (7 * 256 + tid) * 8);

    // ---- B fragments: 4 query-frags of 32 queries per wave ----
    const int qbase = blockIdx.y * QPB;
    const unsigned short* qb = qpack + (((size_t)(qc * 2 + b)) << 18);
    const int qcol = ln & 31, khalf = (ln >> 5) * 8;
    bf16x8 B0 = *(const bf16x8*)(qb + (size_t)(qbase + (wv * 4 + 0) * 32 + qcol) * 16 + khalf);
    bf16x8 B1 = *(const bf16x8*)(qb + (size_t)(qbase + (wv * 4 + 1) * 32 + qcol) * 16 + khalf);
    bf16x8 B2 = *(const bf16x8*)(qb + (size_t)(qbase + (wv * 4 + 2) * 32 + qcol) * 16 + khalf);
    bf16x8 B3 = *(const bf16x8*)(qb + (size_t)(qbase + (wv * 4 + 3) * 32 + qcol) * 16 + khalf);

    *(uint4*)&lds_s[(0 * 256 + tid) * 8] = st0;
    *(uint4*)&lds_s[(1 * 256 + tid) * 8] = st1;
    *(uint4*)&lds_s[(2 * 256 + tid) * 8] = st2;
    *(uint4*)&lds_s[(3 * 256 + tid) * 8] = st3;
    *(uint4*)&lds_s[(4 * 256 + tid) * 8] = st4;
    *(uint4*)&lds_s[(5 * 256 + tid) * 8] = st5;
    *(uint4*)&lds_s[(6 * 256 + tid) * 8] = st6;
    *(uint4*)&lds_s[(7 * 256 + tid) * 8] = st7;
    __syncthreads();

    f32x16 cz = {0.f, 0.f, 0.f, 0.f, 0.f, 0.f, 0.f, 0.f,
                 0.f, 0.f, 0.f, 0.f, 0.f, 0.f, 0.f, 0.f};
    float mA0 = INFINITY, mB0 = INFINITY, mA1 = INFINITY, mB1 = INFINITY;
    float mA2 = INFINITY, mB2 = INFINITY, mA3 = INFINITY, mB3 = INFINITY;

#define FOLD(d, mA, mB)                                       \
    mA = min3(mA, d[0], d[1]);   mB = min3(mB, d[2], d[3]);   \
    mA = min3(mA, d[4], d[5]);   mB = min3(mB, d[6], d[7]);   \
    mA = min3(mA, d[8], d[9]);   mB = min3(mB, d[10], d[11]); \
    mA = min3(mA, d[12], d[13]); mB = min3(mB, d[14], d[15]);

    for (int t = 0; t < TILES; ++t) {
        bf16x8 a = *(const bf16x8*)&lds_s[t * 512 + ln * 8];   // ds_read_b128
        f32x16 d0, d1, d2, d3;
        mfma4(a, B0, B1, B2, B3, cz, d0, d1, d2, d3);
        FOLD(d0, mA0, mB0)
        FOLD(d1, mA1, mB1)
        FOLD(d2, mA2, mB2)
        FOLD(d3, mA3, mB3)
    }
#undef FOLD

    unsigned* om = mins + ((size_t)z << 14) + qbase;
    atomicMin(&om[(wv * 4 + 0) * 32 + qcol], ordf(fminf(mA0, mB0)));
    atomicMin(&om[(wv * 4 + 1) * 32 + qcol], ordf(fminf(mA1, mB1)));
    atomicMin(&om[(wv * 4 + 2) * 32 + qcol], ordf(fminf(mA2, mB2)));
    atomicMin(&om[(wv * 4 + 3) * 32 + qcol], ordf(fminf(mA3, mB3)));
}

// d = sqrt(max(0, 2*(0.5|q|^2 + t_min)))
__global__ __launch_bounds__(256) void reduceA_kernel(const unsigned* __restrict__ mins,
                                                      const float* __restrict__ wq,
                                                      float* __restrict__ partials) {
    int base = blockIdx.x * 1024;
    float s = 0.f;
    #pragma unroll
    for (int k = 0; k < 4; ++k) {
        int t = base + k * 256 + threadIdx.x;
        float m = deordf(mins[t]);
        s += sqrtf(fmaxf(0.f, 2.f * (wq[t] + m)));
    }
    #pragma unroll
    for (int off = 32; off; off >>= 1) s += __shfl_down(s, off);
    __shared__ float wsum[4];
    int lane = threadIdx.x & 63, wv = threadIdx.x >> 6;
    if (lane == 0) wsum[wv] = s;
    __syncthreads();
    if (threadIdx.x == 0) partials[blockIdx.x] = wsum[0] + wsum[1] + wsum[2] + wsum[3];
}

__global__ void reduceB_kernel(const float* __restrict__ partials, float* __restrict__ out) {
    float s = partials[threadIdx.x];
    #pragma unroll
    for (int off = 32; off; off >>= 1) s += __shfl_down(s, off);
    if (threadIdx.x == 0) out[0] = s / (float)TOTQ;
}

extern "C" void kernel_launch(void* const* d_in, const int* in_sizes, int n_in,
                              void* d_out, int out_size, void* d_ws, size_t ws_size,
                              hipStream_t stream) {
    const float* pred   = (const float*)d_in[0];
    const float* target = (const float*)d_in[1];
    char* ws = (char*)d_ws;

    unsigned short* panel = (unsigned short*)ws;                          // 2 MiB
    unsigned short* qpack = (unsigned short*)(ws + (size_t)2 * 1024 * 1024);  // 2 MiB
    float*          wq    = (float*)(ws + (size_t)4 * 1024 * 1024);
    unsigned*       mins  = (unsigned*)(ws + (size_t)4 * 1024 * 1024 + 256 * 1024);
    float*       partials = (float*)(ws + (size_t)4 * 1024 * 1024 + 512 * 1024);
    float* out = (float*)d_out;

    prep_kernel<<<TOTMIN / 256, 256, 0, stream>>>(pred, target, panel, qpack, wq, mins);

    dim3 grid(NRC, NQC, 2 * NB);   // 16 x 32 x 4 = 2048 blocks
    nn_min_kernel<<<grid, 256, 0, stream>>>(panel, qpack, mins);

    reduceA_kernel<<<64, 256, 0, stream>>>(mins, wq, partials);
    reduceB_kernel<<<1, 64, 0, stream>>>(partials, out);
}